// Round 2
// baseline (403.140 us; speedup 1.0000x reference)
//
#include <hip/hip_runtime.h>
#include <hip/hip_bf16.h>
#include <math.h>

typedef unsigned short u16;
typedef u16 u16x8 __attribute__((ext_vector_type(8)));
typedef __bf16 bf16x8 __attribute__((ext_vector_type(8)));
typedef float f32x4 __attribute__((ext_vector_type(4)));

#define MODE_GELU 1
#define MODE_RESF32 2
#define MODE_QKV 3

__device__ __forceinline__ u16 f2bf(float f) {
    unsigned int u = __float_as_uint(f);
    u = (u + 0x7fffu + ((u >> 16) & 1u)) >> 16;
    return (u16)u;
}

__device__ __forceinline__ void gl_lds16(const u16* g, u16* l) {
    __builtin_amdgcn_global_load_lds(
        (const __attribute__((address_space(1))) unsigned int*)(const void*)g,
        (__attribute__((address_space(3))) unsigned int*)(void*)l,
        16, 0, 0);
}

// ---------------------------------------------------------------------------
// Weight transpose + fp32->bf16 convert:  W[K][N] -> WT[N][K] (bf16)
// ---------------------------------------------------------------------------
__global__ __launch_bounds__(256) void wtrans_kernel(
    const float* __restrict__ W, u16* __restrict__ WT, int Krows, int Ncols)
{
    __shared__ float tile[32][33];
    const int k0 = blockIdx.x * 32, n0 = blockIdx.y * 32;
    const int tx = threadIdx.x & 31, ty = threadIdx.x >> 5;  // ty 0..7
#pragma unroll
    for (int j = 0; j < 32; j += 8)
        tile[ty + j][tx] = W[(size_t)(k0 + ty + j) * Ncols + n0 + tx];
    __syncthreads();
#pragma unroll
    for (int j = 0; j < 32; j += 8)
        WT[(size_t)(n0 + ty + j) * Krows + k0 + tx] = f2bf(tile[tx][ty + j]);
}

__global__ __launch_bounds__(256) void bias_concat_kernel(
    const float* __restrict__ a, const float* __restrict__ b,
    const float* __restrict__ c, float* __restrict__ o)
{
    const int t = blockIdx.x * 256 + threadIdx.x;
    if (t < 2304)
        o[t] = t < 768 ? a[t] : (t < 1536 ? b[t - 768] : c[t - 1536]);
}

// ---------------------------------------------------------------------------
// LayerNorm (ddof=1, divide by std+eps, scalar gamma/beta), fp32 -> bf16
// ---------------------------------------------------------------------------
__global__ __launch_bounds__(256) void ln_kernel(
    const float* __restrict__ X, u16* __restrict__ Y,
    const float* __restrict__ gp, const float* __restrict__ bp)
{
    __shared__ float sbuf[8];
    const int row = blockIdx.x, t = threadIdx.x;
    const float* xr = X + (size_t)row * 768;
    float v0 = xr[t], v1 = xr[t + 256], v2 = xr[t + 512];
    float s = v0 + v1 + v2;
    float q = v0 * v0 + v1 * v1 + v2 * v2;
#pragma unroll
    for (int m = 1; m < 64; m <<= 1) {
        s += __shfl_xor(s, m, 64);
        q += __shfl_xor(q, m, 64);
    }
    const int wave = t >> 6, lane = t & 63;
    if (lane == 0) { sbuf[wave] = s; sbuf[4 + wave] = q; }
    __syncthreads();
    s = sbuf[0] + sbuf[1] + sbuf[2] + sbuf[3];
    q = sbuf[4] + sbuf[5] + sbuf[6] + sbuf[7];
    const float mean = s * (1.0f / 768.0f);
    float ssd = q - 768.0f * mean * mean;
    ssd = fmaxf(ssd, 0.0f);
    const float stdv = sqrtf(ssd * (1.0f / 767.0f));
    const float scale = gp[0] / (stdv + 1e-5f);
    const float beta = bp[0];
    u16* yr = Y + (size_t)row * 768;
    yr[t]       = f2bf((v0 - mean) * scale + beta);
    yr[t + 256] = f2bf((v1 - mean) * scale + beta);
    yr[t + 512] = f2bf((v2 - mean) * scale + beta);
}

// ---------------------------------------------------------------------------
// GEMM (m97 structure): C[M][N] = A @ BT^T + bias, global_load_lds staging.
// 128x128 tile, BK=64, 256 thr = 4 waves (2x2), linear LDS [128][64].
// MODE_QKV: N=2304, writes Q,K normal layout and V transposed per-head.
// ---------------------------------------------------------------------------
template <int MODE>
__global__ __launch_bounds__(256) void gemm_kernel(
    const u16* __restrict__ A, const u16* __restrict__ BT,
    const float* __restrict__ bias, const float* __restrict__ res,
    void* __restrict__ out0, void* __restrict__ out1, void* __restrict__ out2,
    int M, int N, int K)
{
    __shared__ u16 As[128 * 64];
    __shared__ u16 Bs[128 * 64];
    const int t = threadIdx.x;
    const int lane = t & 63, wave = t >> 6;
    const int wr = wave >> 1, wc = wave & 1;
    const int g = lane >> 4, c = lane & 15;
    const int bm = blockIdx.x, bn = blockIdx.y;

    // staging: wave w covers rows [w*32, w*32+32), 4 chunks of 8 rows
    const int srow = wave * 32 + (lane >> 3);
    const int scol = (lane & 7) * 8;
    const u16* Ag = A + (size_t)(bm * 128 + srow) * K + scol;
    const u16* Bg = BT + (size_t)(bn * 128 + srow) * K + scol;
    u16* AsW = As + wave * 2048;   // wave-uniform LDS base (elements)
    u16* BsW = Bs + wave * 2048;

    f32x4 acc[4][4] = {};

    for (int k0 = 0; k0 < K; k0 += 64) {
        __syncthreads();
#pragma unroll
        for (int it = 0; it < 4; it++) {
            gl_lds16(Ag + (size_t)(it * 8) * K + k0, AsW + it * 512);
            gl_lds16(Bg + (size_t)(it * 8) * K + k0, BsW + it * 512);
        }
        __syncthreads();
#pragma unroll
        for (int kk = 0; kk < 2; kk++) {
            bf16x8 af[4], bfr[4];
#pragma unroll
            for (int m = 0; m < 4; m++)
                af[m] = *(const bf16x8*)&As[(wr * 64 + m * 16 + c) * 64 + kk * 32 + g * 8];
#pragma unroll
            for (int n = 0; n < 4; n++)
                bfr[n] = *(const bf16x8*)&Bs[(wc * 64 + n * 16 + c) * 64 + kk * 32 + g * 8];
#pragma unroll
            for (int m = 0; m < 4; m++)
#pragma unroll
                for (int n = 0; n < 4; n++)
                    acc[m][n] = __builtin_amdgcn_mfma_f32_16x16x32_bf16(
                        af[m], bfr[n], acc[m][n], 0, 0, 0);
        }
    }

#pragma unroll
    for (int m = 0; m < 4; m++) {
        const int row = bm * 128 + wr * 64 + m * 16 + 4 * g;
#pragma unroll
        for (int n = 0; n < 4; n++) {
            const int col = bn * 128 + wc * 64 + n * 16 + c;
            const float bv = bias[col];
#pragma unroll
            for (int i = 0; i < 4; i++) {
                float v = acc[m][n][i] + bv;
                if constexpr (MODE == MODE_GELU) {
                    v = 0.5f * v * (1.0f + erff(v * 0.70710678118654752f));
                    ((u16*)out0)[(size_t)(row + i) * N + col] = f2bf(v);
                } else if constexpr (MODE == MODE_RESF32) {
                    const size_t idx = (size_t)(row + i) * N + col;
                    ((float*)out0)[idx] = v + res[idx];
                } else {  // MODE_QKV: sections of 768 cols -> Q, K, V^T
                    const int sect = (col >= 1536) ? 2 : (col >= 768 ? 1 : 0);
                    const int colm = col - sect * 768;
                    if (sect == 0) {
                        ((u16*)out0)[(size_t)(row + i) * 768 + colm] = f2bf(v);
                    } else if (sect == 1) {
                        ((u16*)out1)[(size_t)(row + i) * 768 + colm] = f2bf(v);
                    } else {
                        // V^T[(b*12+h)][d][kv], b = rr>>10, kv = rr&1023
                        const int rr = row + i;
                        ((u16*)out2)[((size_t)((rr >> 10) * 12 + (colm >> 6)) << 16)
                                     + ((size_t)(colm & 63) << 10) + (size_t)(rr & 1023)] = f2bf(v);
                    }
                }
            }
        }
    }
}

// ---------------------------------------------------------------------------
// Flash attention: grid (16 q-tiles, 96 b*h), 256 thr = 4 waves x 16 q-rows.
// V pre-transposed per head in global; K/V prefetched one tile ahead.
// ---------------------------------------------------------------------------
__global__ __launch_bounds__(256) void attn_kernel(
    const u16* __restrict__ Q, const u16* __restrict__ Kg,
    const u16* __restrict__ Vt_g, u16* __restrict__ O)
{
    __shared__ u16 Vt[64][72];       // V^T tile: [d][kv]
    __shared__ u16 Pl[4][16][72];    // per-wave P: [q][kv]
    const int t = threadIdx.x, lane = t & 63, wave = t >> 6;
    const int g = lane >> 4, c = lane & 15;
    const int qt = blockIdx.x, bh = blockIdx.y;
    const int b = bh / 12, h = bh % 12;
    const size_t rowb = (size_t)b * 1024;
    const int q0 = qt * 64 + wave * 16;

    bf16x8 qf[2];
    {
        const u16* qp = Q + (rowb + q0 + c) * 768 + h * 64 + g * 8;
        qf[0] = *(const bf16x8*)qp;
        qf[1] = *(const bf16x8*)(qp + 32);
    }

    // V^T staging: thread covers Vt row t>>2, cols (t&3)*16 + {0..15}
    const int vrow = t >> 2, vcol = (t & 3) * 16;
    const u16* vtg = Vt_g + (size_t)bh * 65536 + (size_t)vrow * 1024 + vcol;

    // K fragment base (lane c reads row kv0+n*16+c)
    const u16* kp0 = Kg + (rowb + c) * 768 + h * 64 + g * 8;

    float m_run[4] = {-1e30f, -1e30f, -1e30f, -1e30f};
    float l_run[4] = {0.f, 0.f, 0.f, 0.f};
    f32x4 o_acc[4] = {};

    // prologue: loads for tile 0
    u16x8 vr0 = *(const u16x8*)vtg;
    u16x8 vr1 = *(const u16x8*)(vtg + 8);
    bf16x8 kf[8], kn[8];
#pragma unroll
    for (int n = 0; n < 4; n++) {
        const u16* kp = kp0 + (size_t)(n * 16) * 768;
        kf[2 * n]     = *(const bf16x8*)kp;
        kf[2 * n + 1] = *(const bf16x8*)(kp + 32);
    }

    for (int kvt = 0; kvt < 16; ++kvt) {
        __syncthreads();  // previous PV reads done before Vt overwrite
        *(u16x8*)&Vt[vrow][vcol]     = vr0;
        *(u16x8*)&Vt[vrow][vcol + 8] = vr1;
        if (kvt < 15) {   // issue V loads for next tile (consumed next iter)
            vr0 = *(const u16x8*)(vtg + (kvt + 1) * 64);
            vr1 = *(const u16x8*)(vtg + (kvt + 1) * 64 + 8);
        }
        __syncthreads();  // Vt ready

        // scores S[16 q][64 kv]
        f32x4 s[4] = {};
#pragma unroll
        for (int n = 0; n < 4; n++) {
            s[n] = __builtin_amdgcn_mfma_f32_16x16x32_bf16(qf[0], kf[2 * n],     s[n], 0, 0, 0);
            s[n] = __builtin_amdgcn_mfma_f32_16x16x32_bf16(qf[1], kf[2 * n + 1], s[n], 0, 0, 0);
        }
        // prefetch K for next tile (latency hides under softmax+PV)
        if (kvt < 15) {
            const u16* kpn = kp0 + (size_t)(kvt + 1) * 64 * 768;
#pragma unroll
            for (int n = 0; n < 4; n++) {
                const u16* kp = kpn + (size_t)(n * 16) * 768;
                kn[2 * n]     = *(const bf16x8*)kp;
                kn[2 * n + 1] = *(const bf16x8*)(kp + 32);
            }
        }

        // online softmax (row r = 4*g+i, reduce across the 16 c-lanes)
        float resc[4];
#pragma unroll
        for (int i = 0; i < 4; i++) {
            float mx = fmaxf(fmaxf(s[0][i], s[1][i]), fmaxf(s[2][i], s[3][i]));
#pragma unroll
            for (int msk = 1; msk < 16; msk <<= 1)
                mx = fmaxf(mx, __shfl_xor(mx, msk, 64));
            mx *= 0.125f;
            const float mnew = fmaxf(m_run[i], mx);
            resc[i] = __expf(m_run[i] - mnew);
            m_run[i] = mnew;
            float rs = 0.f;
#pragma unroll
            for (int n = 0; n < 4; n++) {
                const float p = __expf(s[n][i] * 0.125f - mnew);
                rs += p;
                Pl[wave][4 * g + i][n * 16 + c] = f2bf(p);
            }
#pragma unroll
            for (int msk = 1; msk < 16; msk <<= 1)
                rs += __shfl_xor(rs, msk, 64);
            l_run[i] = l_run[i] * resc[i] + rs;
            o_acc[0][i] *= resc[i];
            o_acc[1][i] *= resc[i];
            o_acc[2][i] *= resc[i];
            o_acc[3][i] *= resc[i];
        }

        // PV (Pl wave-private; compiler inserts lgkm waits)
        bf16x8 pa0 = *(const bf16x8*)&Pl[wave][c][g * 8];
        bf16x8 pa1 = *(const bf16x8*)&Pl[wave][c][32 + g * 8];
#pragma unroll
        for (int n = 0; n < 4; n++) {
            bf16x8 vf0 = *(const bf16x8*)&Vt[n * 16 + c][g * 8];
            bf16x8 vf1 = *(const bf16x8*)&Vt[n * 16 + c][32 + g * 8];
            o_acc[n] = __builtin_amdgcn_mfma_f32_16x16x32_bf16(pa0, vf0, o_acc[n], 0, 0, 0);
            o_acc[n] = __builtin_amdgcn_mfma_f32_16x16x32_bf16(pa1, vf1, o_acc[n], 0, 0, 0);
        }
#pragma unroll
        for (int j = 0; j < 8; j++) kf[j] = kn[j];
    }

#pragma unroll
    for (int i = 0; i < 4; i++) {
        const float inv = 1.0f / l_run[i];
        const size_t row = rowb + q0 + 4 * g + i;
#pragma unroll
        for (int n = 0; n < 4; n++)
            O[row * 768 + h * 64 + n * 16 + c] = f2bf(o_acc[n][i] * inv);
    }
}

// ---------------------------------------------------------------------------
// Launch
// ---------------------------------------------------------------------------
extern "C" void kernel_launch(void* const* d_in, const int* in_sizes, int n_in,
                              void* d_out, int out_size, void* d_ws, size_t ws_size,
                              hipStream_t stream)
{
    const float* x   = (const float*)d_in[0];
    const float* wq  = (const float*)d_in[1];
    const float* bq  = (const float*)d_in[2];
    const float* wk  = (const float*)d_in[3];
    const float* bk  = (const float*)d_in[4];
    const float* wv  = (const float*)d_in[5];
    const float* bv  = (const float*)d_in[6];
    const float* wo  = (const float*)d_in[7];
    const float* bo  = (const float*)d_in[8];
    const float* w1  = (const float*)d_in[9];
    const float* b1  = (const float*)d_in[10];
    const float* w2  = (const float*)d_in[11];
    const float* b2  = (const float*)d_in[12];
    const float* g1  = (const float*)d_in[13];
    const float* be1 = (const float*)d_in[14];
    const float* g2  = (const float*)d_in[15];
    const float* be2 = (const float*)d_in[16];

    char* ws = (char*)d_ws;
    constexpr size_t O_WQKV = 0;                       // [2304][768] bf16
    constexpr size_t O_WO   = 3538944;                 // [768][768]  bf16
    constexpr size_t O_W1   = 4718592;                 // [3072][768] bf16
    constexpr size_t O_W2   = 9437184;                 // [768][3072] bf16
    constexpr size_t O_BQKV = 14155776;                // [2304] f32
    constexpr size_t O_XLN  = 14168064;                // [8192][768] bf16
    constexpr size_t O_Q    = O_XLN + 12582912;
    constexpr size_t O_K    = O_Q + 12582912;
    constexpr size_t O_VT   = O_K + 12582912;          // [96][64][1024] bf16
    constexpr size_t O_ATTN = O_VT + 12582912;
    constexpr size_t O_H    = O_ATTN + 12582912;       // [8192][768] f32
    constexpr size_t O_F    = O_XLN;                   // [8192][3072] bf16 overlays xln..VT
    constexpr size_t O_HLN  = O_ATTN;                  // overlays attnb

    u16* wqkvT = (u16*)(ws + O_WQKV);
    u16* woT   = (u16*)(ws + O_WO);
    u16* w1T   = (u16*)(ws + O_W1);
    u16* w2T   = (u16*)(ws + O_W2);
    float* bqkv = (float*)(ws + O_BQKV);
    u16* xln   = (u16*)(ws + O_XLN);
    u16* Qb    = (u16*)(ws + O_Q);
    u16* Kb    = (u16*)(ws + O_K);
    u16* VTg   = (u16*)(ws + O_VT);
    u16* attnb = (u16*)(ws + O_ATTN);
    float* h   = (float*)(ws + O_H);
    u16* fb    = (u16*)(ws + O_F);
    u16* hln   = (u16*)(ws + O_HLN);

    dim3 blk(256);
    // weight transposes (W[K][N] -> WT[N][K] bf16); QKV concatenated row-wise
    wtrans_kernel<<<dim3(24, 24), blk, 0, stream>>>(wq, wqkvT, 768, 768);
    wtrans_kernel<<<dim3(24, 24), blk, 0, stream>>>(wk, wqkvT + (size_t)768 * 768, 768, 768);
    wtrans_kernel<<<dim3(24, 24), blk, 0, stream>>>(wv, wqkvT + (size_t)1536 * 768, 768, 768);
    wtrans_kernel<<<dim3(24, 24), blk, 0, stream>>>(wo, woT, 768, 768);
    wtrans_kernel<<<dim3(24, 96), blk, 0, stream>>>(w1, w1T, 768, 3072);
    wtrans_kernel<<<dim3(96, 24), blk, 0, stream>>>(w2, w2T, 3072, 768);
    bias_concat_kernel<<<9, blk, 0, stream>>>(bq, bk, bv, bqkv);

    // LN1
    ln_kernel<<<8192, blk, 0, stream>>>(x, xln, g1, be1);
    // fused QKV projection (V written transposed per-head)
    gemm_kernel<MODE_QKV><<<dim3(64, 18), blk, 0, stream>>>(
        xln, wqkvT, bqkv, nullptr, Qb, Kb, VTg, 8192, 2304, 768);
    // attention
    attn_kernel<<<dim3(16, 96), blk, 0, stream>>>(Qb, Kb, VTg, attnb);
    // output projection + residual -> h (fp32)
    gemm_kernel<MODE_RESF32><<<dim3(64, 6), blk, 0, stream>>>(
        attnb, woT, bo, x, h, nullptr, nullptr, 8192, 768, 768);
    // LN2
    ln_kernel<<<8192, blk, 0, stream>>>(h, hln, g2, be2);
    // FFN1 + GELU
    gemm_kernel<MODE_GELU><<<dim3(64, 24), blk, 0, stream>>>(
        hln, w1T, b1, nullptr, fb, nullptr, nullptr, 8192, 3072, 768);
    // FFN2 + residual -> out (fp32)
    gemm_kernel<MODE_RESF32><<<dim3(64, 6), blk, 0, stream>>>(
        fb, w2T, b2, h, (float*)d_out, nullptr, nullptr, 8192, 768, 3072);
}

// Round 5
// 377.615 us; speedup vs baseline: 1.0676x; 1.0676x over previous
//
#include <hip/hip_runtime.h>
#include <hip/hip_bf16.h>
#include <math.h>

typedef unsigned short u16;
typedef unsigned int u32;
typedef u16 u16x8 __attribute__((ext_vector_type(8)));
typedef __bf16 bf16x8 __attribute__((ext_vector_type(8)));
typedef float f32x4 __attribute__((ext_vector_type(4)));
typedef u32 u32x4 __attribute__((ext_vector_type(4)));

#define MODE_GELU 1
#define MODE_RESF32 2
#define MODE_QKV 3

template <typename T, typename F>
__device__ __forceinline__ T bitcast(F f) { return __builtin_bit_cast(T, f); }

__device__ __forceinline__ u16 f2bf(float f) {
    unsigned int u = __float_as_uint(f);
    u = (u + 0x7fffu + ((u >> 16) & 1u)) >> 16;
    return (u16)u;
}

// pack two floats into (lo | hi<<16) bf16 pair — pure C, no inline asm
__device__ __forceinline__ u32 packbf(float lo, float hi) {
    return (u32)f2bf(lo) | ((u32)f2bf(hi) << 16);
}

__device__ __forceinline__ void gl_lds16(const u16* g, u16* l) {
    __builtin_amdgcn_global_load_lds(
        (const __attribute__((address_space(1))) unsigned int*)(const void*)g,
        (__attribute__((address_space(3))) unsigned int*)(void*)l,
        16, 0, 0);
}

// ---------------------------------------------------------------------------
// Weight transpose + fp32->bf16 convert:  W[K][N] -> WT[N][K] (bf16)
// ---------------------------------------------------------------------------
__global__ __launch_bounds__(256) void wtrans_kernel(
    const float* __restrict__ W, u16* __restrict__ WT, int Krows, int Ncols)
{
    __shared__ float tile[32][33];
    const int k0 = blockIdx.x * 32, n0 = blockIdx.y * 32;
    const int tx = threadIdx.x & 31, ty = threadIdx.x >> 5;
#pragma unroll
    for (int j = 0; j < 32; j += 8)
        tile[ty + j][tx] = W[(size_t)(k0 + ty + j) * Ncols + n0 + tx];
    __syncthreads();
#pragma unroll
    for (int j = 0; j < 32; j += 8)
        WT[(size_t)(n0 + ty + j) * Krows + k0 + tx] = f2bf(tile[tx][ty + j]);
}

__global__ __launch_bounds__(256) void bias_concat_kernel(
    const float* __restrict__ a, const float* __restrict__ b,
    const float* __restrict__ c, float* __restrict__ o)
{
    const int t = blockIdx.x * 256 + threadIdx.x;
    if (t < 2304)
        o[t] = t < 768 ? a[t] : (t < 1536 ? b[t - 768] : c[t - 1536]);
}

// ---------------------------------------------------------------------------
// LayerNorm (ddof=1, divide by std+eps, scalar gamma/beta), fp32 -> bf16
// ---------------------------------------------------------------------------
__global__ __launch_bounds__(256) void ln_kernel(
    const float* __restrict__ X, u16* __restrict__ Y,
    const float* __restrict__ gp, const float* __restrict__ bp)
{
    __shared__ float sbuf[8];
    const int row = blockIdx.x, t = threadIdx.x;
    const float* xr = X + (size_t)row * 768;
    float v0 = xr[t], v1 = xr[t + 256], v2 = xr[t + 512];
    float s = v0 + v1 + v2;
    float q = v0 * v0 + v1 * v1 + v2 * v2;
#pragma unroll
    for (int m = 1; m < 64; m <<= 1) {
        s += __shfl_xor(s, m, 64);
        q += __shfl_xor(q, m, 64);
    }
    const int wave = t >> 6, lane = t & 63;
    if (lane == 0) { sbuf[wave] = s; sbuf[4 + wave] = q; }
    __syncthreads();
    s = sbuf[0] + sbuf[1] + sbuf[2] + sbuf[3];
    q = sbuf[4] + sbuf[5] + sbuf[6] + sbuf[7];
    const float mean = s * (1.0f / 768.0f);
    float ssd = q - 768.0f * mean * mean;
    ssd = fmaxf(ssd, 0.0f);
    const float stdv = sqrtf(ssd * (1.0f / 767.0f));
    const float scale = gp[0] / (stdv + 1e-5f);
    const float beta = bp[0];
    u16* yr = Y + (size_t)row * 768;
    yr[t]       = f2bf((v0 - mean) * scale + beta);
    yr[t + 256] = f2bf((v1 - mean) * scale + beta);
    yr[t + 512] = f2bf((v2 - mean) * scale + beta);
}

// ---------------------------------------------------------------------------
// GEMM (m97 structure): C[M][N] = A @ BT^T + bias, global_load_lds staging.
// 128x128 tile, BK=64, 256 thr = 4 waves (2x2), linear LDS.
// MODE_QKV: N=2304; Q/K written normal; V written transposed per-head via
// LDS-staged tile transpose (coalesced V^T stores).
// ---------------------------------------------------------------------------
template <int MODE>
__global__ __launch_bounds__(256) void gemm_kernel(
    const u16* __restrict__ A, const u16* __restrict__ BT,
    const float* __restrict__ bias, const float* __restrict__ res,
    void* __restrict__ out0, void* __restrict__ out1, void* __restrict__ out2,
    int M, int N, int K)
{
    __shared__ u16 sh[2 * 128 * 64];          // As | Bs; reused for V-transpose
    u16* Asb = sh;
    u16* Bsb = sh + 8192;
    const int t = threadIdx.x;
    const int lane = t & 63, wave = t >> 6;
    const int wr = wave >> 1, wc = wave & 1;
    const int g = lane >> 4, c = lane & 15;
    const int bm = blockIdx.x, bn = blockIdx.y;

    const int srow = wave * 32 + (lane >> 3);
    const int scol = (lane & 7) * 8;
    const u16* Ag = A + (size_t)(bm * 128 + srow) * K + scol;
    const u16* Bg = BT + (size_t)(bn * 128 + srow) * K + scol;
    u16* AsW = Asb + wave * 2048;
    u16* BsW = Bsb + wave * 2048;

    f32x4 acc[4][4] = {};

    for (int k0 = 0; k0 < K; k0 += 64) {
        __syncthreads();
#pragma unroll
        for (int it = 0; it < 4; it++) {
            gl_lds16(Ag + (size_t)(it * 8) * K + k0, AsW + it * 512);
            gl_lds16(Bg + (size_t)(it * 8) * K + k0, BsW + it * 512);
        }
        __syncthreads();
#pragma unroll
        for (int kk = 0; kk < 2; kk++) {
            bf16x8 af[4], bfr[4];
#pragma unroll
            for (int m = 0; m < 4; m++)
                af[m] = *(const bf16x8*)&Asb[(wr * 64 + m * 16 + c) * 64 + kk * 32 + g * 8];
#pragma unroll
            for (int n = 0; n < 4; n++)
                bfr[n] = *(const bf16x8*)&Bsb[(wc * 64 + n * 16 + c) * 64 + kk * 32 + g * 8];
#pragma unroll
            for (int m = 0; m < 4; m++)
#pragma unroll
                for (int n = 0; n < 4; n++)
                    acc[m][n] = __builtin_amdgcn_mfma_f32_16x16x32_bf16(
                        af[m], bfr[n], acc[m][n], 0, 0, 0);
        }
    }

    if constexpr (MODE == MODE_QKV) {
        if (bn >= 12) {
            // ---- V section: LDS tile transpose, coalesced V^T stores ----
            __syncthreads();
#pragma unroll
            for (int m = 0; m < 4; m++) {
#pragma unroll
                for (int n = 0; n < 4; n++) {
                    const int colL = wc * 64 + n * 16 + c;
                    const int rowLb = wr * 64 + m * 16 + 4 * g;
                    const float bv = bias[bn * 128 + colL];
                    const u32 x0 = packbf(acc[m][n][0] + bv, acc[m][n][1] + bv);
                    const u32 x1 = packbf(acc[m][n][2] + bv, acc[m][n][3] + bv);
                    const int elem = colL * 128 + (rowLb ^ ((colL & 15) << 3));
                    ((u32*)sh)[elem >> 1] = x0;
                    ((u32*)sh)[(elem >> 1) + 1] = x1;
                }
            }
            __syncthreads();
            const int bn_off = bn - 12;
            const int bb = bm >> 3, kvb = (bm & 7) * 128;
            const int j8 = (t & 7) * 8;
#pragma unroll
            for (int it = 0; it < 4; it++) {
                const int colL2 = it * 32 + (t >> 3);
                const int gcol = bn_off * 128 + colL2;
                const int hh = gcol >> 6, d = gcol & 63;
                const size_t obase = ((size_t)(bb * 12 + hh) << 16) + ((size_t)d << 10) + kvb;
                const int X = (colL2 & 15) << 3;
#pragma unroll
                for (int half = 0; half < 2; half++) {
                    const int rowL2 = half * 64 + j8;
                    const int elem = colL2 * 128 + (rowL2 ^ X);
                    *(u16x8*)((u16*)out2 + obase + rowL2) = *(const u16x8*)&sh[elem];
                }
            }
            return;
        }
    }

#pragma unroll
    for (int m = 0; m < 4; m++) {
        const int row = bm * 128 + wr * 64 + m * 16 + 4 * g;
#pragma unroll
        for (int n = 0; n < 4; n++) {
            const int col = bn * 128 + wc * 64 + n * 16 + c;
            const float bv = bias[col];
#pragma unroll
            for (int i = 0; i < 4; i++) {
                float v = acc[m][n][i] + bv;
                if constexpr (MODE == MODE_GELU) {
                    v = 0.5f * v * (1.0f + erff(v * 0.70710678118654752f));
                    ((u16*)out0)[(size_t)(row + i) * N + col] = f2bf(v);
                } else if constexpr (MODE == MODE_RESF32) {
                    const size_t idx = (size_t)(row + i) * N + col;
                    ((float*)out0)[idx] = v + res[idx];
                } else {  // MODE_QKV, bn < 12: Q or K, normal layout
                    const int sect = (col >= 768) ? 1 : 0;
                    const int colm = col - sect * 768;
                    u16* dst = sect ? (u16*)out1 : (u16*)out0;
                    dst[(size_t)(row + i) * 768 + colm] = f2bf(v);
                }
            }
        }
    }
}

// ---------------------------------------------------------------------------
// Flash attention, swapped QK^T + in-register softmax.
// grid (16 q-tiles, 96 b*h), 256 thr = 4 waves x 16 q-rows, KV tile 64.
// mfma(K,Q): lane holds S[kv][q=c]; K-rows permuted so P lands directly in
// the PV A-fragment layout (no cross-lane P movement).
// ---------------------------------------------------------------------------
__global__ __launch_bounds__(256) void attn_kernel(
    const u16* __restrict__ Q, const u16* __restrict__ Kg,
    const u16* __restrict__ Vt_g, u16* __restrict__ O)
{
    __shared__ u16 Vt[64][72];       // V^T tile: [d][kv]
    const int t = threadIdx.x, lane = t & 63, wave = t >> 6;
    const int g = lane >> 4, c = lane & 15;
    const int qt = blockIdx.x, bh = blockIdx.y;
    const int b = bh / 12, h = bh % 12;
    const size_t rowb = (size_t)b * 1024;
    const int q0 = qt * 64 + wave * 16;

    // Q fragment scaled by 0.125*log2(e) (scores land in exp2 units)
    bf16x8 qf[2];
    {
        const u16* qp = Q + (rowb + q0 + c) * 768 + h * 64 + g * 8;
        u16x8 r0 = *(const u16x8*)qp;
        u16x8 r1 = *(const u16x8*)(qp + 32);
        u16x8 q0v, q1v;
#pragma unroll
        for (int j = 0; j < 8; j++) {
            q0v[j] = f2bf(__uint_as_float(((u32)r0[j]) << 16) * 0.18033688011112042f);
            q1v[j] = f2bf(__uint_as_float(((u32)r1[j]) << 16) * 0.18033688011112042f);
        }
        qf[0] = bitcast<bf16x8>(q0v);
        qf[1] = bitcast<bf16x8>(q1v);
    }

    // V^T staging
    const int vrow = t >> 2, vcol = (t & 3) * 16;
    const u16* vtg = Vt_g + (size_t)bh * 65536 + (size_t)vrow * 1024 + vcol;

    // K rows permuted: frag row c of mfma n -> kv = (n>>1)*32+(c>>2)*8+(n&1)*4+(c&3)
    const u16* kbase = Kg + rowb * 768 + h * 64 + g * 8;
    int kro[4];
#pragma unroll
    for (int n = 0; n < 4; n++)
        kro[n] = ((n >> 1) * 32 + ((c >> 2) * 8) + ((n & 1) * 4) + (c & 3)) * 768;

    float m_run = -1e30f, l_run = 0.f;
    f32x4 o_acc[4] = {};

    // prologue loads (tile 0)
    u16x8 vr0 = *(const u16x8*)vtg;
    u16x8 vr1 = *(const u16x8*)(vtg + 8);
    bf16x8 kf[8], kn[8];
#pragma unroll
    for (int n = 0; n < 4; n++) {
        kf[2 * n]     = *(const bf16x8*)(kbase + kro[n]);
        kf[2 * n + 1] = *(const bf16x8*)(kbase + kro[n] + 32);
    }

    const int srcb = (lane & 48) | ((lane >> 2) & 12);   // = 20*g

    for (int kvt = 0; kvt < 16; ++kvt) {
        __syncthreads();  // previous PV reads done before Vt overwrite
        *(u16x8*)&Vt[vrow][vcol]     = vr0;
        *(u16x8*)&Vt[vrow][vcol + 8] = vr1;
        if (kvt < 15) {
            vr0 = *(const u16x8*)(vtg + (kvt + 1) * 64);
            vr1 = *(const u16x8*)(vtg + (kvt + 1) * 64 + 8);
        }
        __syncthreads();  // Vt ready

        // S^T[kv][q=c]: s[n][i] = S[kv0 + perm(n,4g+i)][q0+c] (exp2 units)
        f32x4 s[4] = {};
#pragma unroll
        for (int n = 0; n < 4; n++) {
            s[n] = __builtin_amdgcn_mfma_f32_16x16x32_bf16(kf[2 * n],     qf[0], s[n], 0, 0, 0);
            s[n] = __builtin_amdgcn_mfma_f32_16x16x32_bf16(kf[2 * n + 1], qf[1], s[n], 0, 0, 0);
        }
        // prefetch next K tile
        if (kvt < 15) {
            const u16* kpn = kbase + (size_t)(kvt + 1) * 64 * 768;
#pragma unroll
            for (int n = 0; n < 4; n++) {
                kn[2 * n]     = *(const bf16x8*)(kpn + kro[n]);
                kn[2 * n + 1] = *(const bf16x8*)(kpn + kro[n] + 32);
            }
        }

        // in-register online softmax for row q=c
        float mx = s[0][0];
#pragma unroll
        for (int n = 0; n < 4; n++)
#pragma unroll
            for (int i = 0; i < 4; i++) mx = fmaxf(mx, s[n][i]);
        mx = fmaxf(mx, __shfl_xor(mx, 16, 64));
        mx = fmaxf(mx, __shfl_xor(mx, 32, 64));
        const float mnew = fmaxf(m_run, mx);
        const float resc = exp2f(m_run - mnew);
        m_run = mnew;
        float rs = 0.f;
#pragma unroll
        for (int n = 0; n < 4; n++)
#pragma unroll
            for (int i = 0; i < 4; i++) {
                const float p = exp2f(fminf(s[n][i] - mnew, 0.0f));
                s[n][i] = p;
                rs += p;
            }
        rs += __shfl_xor(rs, 16, 64);
        rs += __shfl_xor(rs, 32, 64);
        l_run = l_run * resc + rs;

        // rescale o_acc rows (row i holds q = 4*g+i; resc lives at lane srcb+i)
        f32x4 rq;
#pragma unroll
        for (int i = 0; i < 4; i++) rq[i] = __shfl(resc, srcb + i, 64);
#pragma unroll
        for (int n = 0; n < 4; n++) o_acc[n] *= rq;

        // pack P into PV A-fragments (lane-local by construction)
        u32x4 pw0, pw1;
        pw0[0] = packbf(s[0][0], s[0][1]); pw0[1] = packbf(s[0][2], s[0][3]);
        pw0[2] = packbf(s[1][0], s[1][1]); pw0[3] = packbf(s[1][2], s[1][3]);
        pw1[0] = packbf(s[2][0], s[2][1]); pw1[1] = packbf(s[2][2], s[2][3]);
        pw1[2] = packbf(s[3][0], s[3][1]); pw1[3] = packbf(s[3][2], s[3][3]);
        const bf16x8 pa0 = bitcast<bf16x8>(pw0);
        const bf16x8 pa1 = bitcast<bf16x8>(pw1);

        // PV
#pragma unroll
        for (int n = 0; n < 4; n++) {
            bf16x8 vf0 = *(const bf16x8*)&Vt[n * 16 + c][g * 8];
            bf16x8 vf1 = *(const bf16x8*)&Vt[n * 16 + c][32 + g * 8];
            o_acc[n] = __builtin_amdgcn_mfma_f32_16x16x32_bf16(pa0, vf0, o_acc[n], 0, 0, 0);
            o_acc[n] = __builtin_amdgcn_mfma_f32_16x16x32_bf16(pa1, vf1, o_acc[n], 0, 0, 0);
        }
#pragma unroll
        for (int j = 0; j < 8; j++) kf[j] = kn[j];
    }

#pragma unroll
    for (int i = 0; i < 4; i++) {
        const float li = __shfl(l_run, srcb + i, 64);
        const float inv = 1.0f / fmaxf(li, 1e-30f);
        const size_t row = rowb + q0 + 4 * g + i;
#pragma unroll
        for (int n = 0; n < 4; n++)
            O[row * 768 + h * 64 + n * 16 + c] = f2bf(o_acc[n][i] * inv);
    }
}

// ---------------------------------------------------------------------------
// Launch
// ---------------------------------------------------------------------------
extern "C" void kernel_launch(void* const* d_in, const int* in_sizes, int n_in,
                              void* d_out, int out_size, void* d_ws, size_t ws_size,
                              hipStream_t stream)
{
    const float* x   = (const float*)d_in[0];
    const float* wq  = (const float*)d_in[1];
    const float* bq  = (const float*)d_in[2];
    const float* wk  = (const float*)d_in[3];
    const float* bk  = (const float*)d_in[4];
    const float* wv  = (const float*)d_in[5];
    const float* bv  = (const float*)d_in[6];
    const float* wo  = (const float*)d_in[7];
    const float* bo  = (const float*)d_in[8];
    const float* w1  = (const float*)d_in[9];
    const float* b1  = (const float*)d_in[10];
    const float* w2  = (const float*)d_in[11];
    const float* b2  = (const float*)d_in[12];
    const float* g1  = (const float*)d_in[13];
    const float* be1 = (const float*)d_in[14];
    const float* g2  = (const float*)d_in[15];
    const float* be2 = (const float*)d_in[16];

    char* ws = (char*)d_ws;
    constexpr size_t O_WQKV = 0;                       // [2304][768] bf16
    constexpr size_t O_WO   = 3538944;                 // [768][768]  bf16
    constexpr size_t O_W1   = 4718592;                 // [3072][768] bf16
    constexpr size_t O_W2   = 9437184;                 // [768][3072] bf16
    constexpr size_t O_BQKV = 14155776;                // [2304] f32
    constexpr size_t O_XLN  = 14168064;                // [8192][768] bf16
    constexpr size_t O_Q    = O_XLN + 12582912;
    constexpr size_t O_K    = O_Q + 12582912;
    constexpr size_t O_VT   = O_K + 12582912;          // [96][64][1024] bf16
    constexpr size_t O_ATTN = O_VT + 12582912;
    constexpr size_t O_H    = O_ATTN + 12582912;       // [8192][768] f32
    constexpr size_t O_F    = O_XLN;                   // overlays xln..VT
    constexpr size_t O_HLN  = O_ATTN;                  // overlays attnb

    u16* wqkvT = (u16*)(ws + O_WQKV);
    u16* woT   = (u16*)(ws + O_WO);
    u16* w1T   = (u16*)(ws + O_W1);
    u16* w2T   = (u16*)(ws + O_W2);
    float* bqkv = (float*)(ws + O_BQKV);
    u16* xln   = (u16*)(ws + O_XLN);
    u16* Qb    = (u16*)(ws + O_Q);
    u16* Kb    = (u16*)(ws + O_K);
    u16* VTg   = (u16*)(ws + O_VT);
    u16* attnb = (u16*)(ws + O_ATTN);
    float* h   = (float*)(ws + O_H);
    u16* fb    = (u16*)(ws + O_F);
    u16* hln   = (u16*)(ws + O_HLN);

    dim3 blk(256);
    wtrans_kernel<<<dim3(24, 24), blk, 0, stream>>>(wq, wqkvT, 768, 768);
    wtrans_kernel<<<dim3(24, 24), blk, 0, stream>>>(wk, wqkvT + (size_t)768 * 768, 768, 768);
    wtrans_kernel<<<dim3(24, 24), blk, 0, stream>>>(wv, wqkvT + (size_t)1536 * 768, 768, 768);
    wtrans_kernel<<<dim3(24, 24), blk, 0, stream>>>(wo, woT, 768, 768);
    wtrans_kernel<<<dim3(24, 96), blk, 0, stream>>>(w1, w1T, 768, 3072);
    wtrans_kernel<<<dim3(96, 24), blk, 0, stream>>>(w2, w2T, 3072, 768);
    bias_concat_kernel<<<9, blk, 0, stream>>>(bq, bk, bv, bqkv);

    ln_kernel<<<8192, blk, 0, stream>>>(x, xln, g1, be1);
    gemm_kernel<MODE_QKV><<<dim3(64, 18), blk, 0, stream>>>(
        xln, wqkvT, bqkv, nullptr, Qb, Kb, VTg, 8192, 2304, 768);
    attn_kernel<<<dim3(16, 96), blk, 0, stream>>>(Qb, Kb, VTg, attnb);
    gemm_kernel<MODE_RESF32><<<dim3(64, 6), blk, 0, stream>>>(
        attnb, woT, bo, x, h, nullptr, nullptr, 8192, 768, 768);
    ln_kernel<<<8192, blk, 0, stream>>>(h, hln, g2, be2);
    gemm_kernel<MODE_GELU><<<dim3(64, 24), blk, 0, stream>>>(
        hln, w1T, b1, nullptr, fb, nullptr, nullptr, 8192, 3072, 768);
    gemm_kernel<MODE_RESF32><<<dim3(64, 6), blk, 0, stream>>>(
        fb, w2T, b2, h, (float*)d_out, nullptr, nullptr, 8192, 768, 3072);
}